// Round 1
// baseline (549.897 us; speedup 1.0000x reference)
//
#include <hip/hip_runtime.h>
#include <math.h>

// Problem constants
#define NCOL 32768          // N = 32*32*32 columns
#define KAT  512            // dictionary atoms
#define DIM  64             // embedding dim
#define CPB  8              // columns per omp block (LDS 18.4 KB -> 8 blocks/CU)

// Output flat offsets (fp32 elements)
#define O_LOSS  0
#define O_RECON 1
#define O_ZF    2097153     // 1 + 2097152
#define O_PERP  4194305
#define O_GAMMA 4194306

// Workspace layout (fp32 elements)
#define WS_DN   0           // Dn  [64][512]
#define WS_DNT  32768       // DnT [512][64]
#define WS_G    65536       // G   [512][512]
#define WS_ACC  327680      // acc[0]=sum((recon-zf)^2), acc[1]=sum_n S_n

// ---------------------------------------------------------------------------
// DPP wave-64 reductions (all-VALU; result broadcast via readlane)
__device__ __forceinline__ float wave_max_bcast_f32(float v) {
    int x = __float_as_int(v);
    int t;
    t = __builtin_amdgcn_update_dpp(x, x, 0x111, 0xf, 0xf, false);  // row_shr:1
    x = __float_as_int(fmaxf(__int_as_float(x), __int_as_float(t)));
    t = __builtin_amdgcn_update_dpp(x, x, 0x112, 0xf, 0xf, false);  // row_shr:2
    x = __float_as_int(fmaxf(__int_as_float(x), __int_as_float(t)));
    t = __builtin_amdgcn_update_dpp(x, x, 0x114, 0xf, 0xf, false);  // row_shr:4
    x = __float_as_int(fmaxf(__int_as_float(x), __int_as_float(t)));
    t = __builtin_amdgcn_update_dpp(x, x, 0x118, 0xf, 0xf, false);  // row_shr:8
    x = __float_as_int(fmaxf(__int_as_float(x), __int_as_float(t)));
    t = __builtin_amdgcn_update_dpp(x, x, 0x142, 0xa, 0xf, false);  // row_bcast:15
    x = __float_as_int(fmaxf(__int_as_float(x), __int_as_float(t)));
    t = __builtin_amdgcn_update_dpp(x, x, 0x143, 0xc, 0xf, false);  // row_bcast:31
    x = __float_as_int(fmaxf(__int_as_float(x), __int_as_float(t)));
    return __int_as_float(__builtin_amdgcn_readlane(x, 63));
}

__device__ __forceinline__ unsigned wave_min_bcast_u32(unsigned v) {
    int x = (int)v;
    int t;
    t = __builtin_amdgcn_update_dpp(x, x, 0x111, 0xf, 0xf, false);
    x = (int)min((unsigned)x, (unsigned)t);
    t = __builtin_amdgcn_update_dpp(x, x, 0x112, 0xf, 0xf, false);
    x = (int)min((unsigned)x, (unsigned)t);
    t = __builtin_amdgcn_update_dpp(x, x, 0x114, 0xf, 0xf, false);
    x = (int)min((unsigned)x, (unsigned)t);
    t = __builtin_amdgcn_update_dpp(x, x, 0x118, 0xf, 0xf, false);
    x = (int)min((unsigned)x, (unsigned)t);
    t = __builtin_amdgcn_update_dpp(x, x, 0x142, 0xa, 0xf, false);
    x = (int)min((unsigned)x, (unsigned)t);
    t = __builtin_amdgcn_update_dpp(x, x, 0x143, 0xc, 0xf, false);
    x = (int)min((unsigned)x, (unsigned)t);
    return (unsigned)__builtin_amdgcn_readlane(x, 63);
}

// Full-wave sum, result valid at lane 63, returned uniform via readlane.
// xor1/xor2 via quad_perm, xor4 via row_half_mirror, xor8 via row_mirror
// (after xor1..4 all lanes of an 8-group hold the same value, so mirror == xor8),
// then the two row_bcast stages as in wave_max.
__device__ __forceinline__ float wave_sum_bcast_f32(float v) {
    int x = __float_as_int(v);
    int t;
    t = __builtin_amdgcn_update_dpp(x, x, 0x0B1, 0xf, 0xf, false);  // quad_perm [1,0,3,2]
    x = __float_as_int(__int_as_float(x) + __int_as_float(t));
    t = __builtin_amdgcn_update_dpp(x, x, 0x04E, 0xf, 0xf, false);  // quad_perm [2,3,0,1]
    x = __float_as_int(__int_as_float(x) + __int_as_float(t));
    t = __builtin_amdgcn_update_dpp(x, x, 0x141, 0xf, 0xf, false);  // row_half_mirror
    x = __float_as_int(__int_as_float(x) + __int_as_float(t));
    t = __builtin_amdgcn_update_dpp(x, x, 0x140, 0xf, 0xf, false);  // row_mirror
    x = __float_as_int(__int_as_float(x) + __int_as_float(t));
    t = __builtin_amdgcn_update_dpp(x, x, 0x142, 0xa, 0xf, false);  // row_bcast:15
    x = __float_as_int(__int_as_float(x) + __int_as_float(t));
    t = __builtin_amdgcn_update_dpp(x, x, 0x143, 0xc, 0xf, false);  // row_bcast:31
    x = __float_as_int(__int_as_float(x) + __int_as_float(t));
    return __int_as_float(__builtin_amdgcn_readlane(x, 63));
}

// Sum over each 8-lane group, result on ALL lanes of the group (3 DPP stages).
__device__ __forceinline__ float sum8_all_f32(float v) {
    int x = __float_as_int(v);
    int t;
    t = __builtin_amdgcn_update_dpp(x, x, 0x0B1, 0xf, 0xf, false);  // xor1
    x = __float_as_int(__int_as_float(x) + __int_as_float(t));
    t = __builtin_amdgcn_update_dpp(x, x, 0x04E, 0xf, 0xf, false);  // xor2
    x = __float_as_int(__int_as_float(x) + __int_as_float(t));
    t = __builtin_amdgcn_update_dpp(x, x, 0x141, 0xf, 0xf, false);  // xor4 (half_mirror)
    x = __float_as_int(__int_as_float(x) + __int_as_float(t));
    return __int_as_float(x);
}

// ---------------------------------------------------------------------------
// Kernel 1: normalize dictionary columns -> Dn, DnT; zero accumulators.
// 8 blocks x 64 threads (was 1x512: single-CU latency-serial).
__global__ void prep_kernel(const float* __restrict__ dict, float* __restrict__ ws) {
    float* Dn  = ws + WS_DN;
    float* DnT = ws + WS_DNT;
    float* acc = ws + WS_ACC;
    int a = blockIdx.x * 64 + threadIdx.x;
    if (blockIdx.x == 0 && threadIdx.x < 2) acc[threadIdx.x] = 0.f;
    float s = 0.f;
    #pragma unroll
    for (int d = 0; d < DIM; ++d) { float v = dict[d*KAT + a]; s += v * v; }
    float nrm = sqrtf(s);
    #pragma unroll
    for (int d = 0; d < DIM; ++d) {
        float v = dict[d*KAT + a] / nrm;
        Dn[d*KAT + a]  = v;
        DnT[a*DIM + d] = v;
    }
}

// ---------------------------------------------------------------------------
// Kernel 2: G = Dn^T Dn.  block = row i (512 blocks), thread = col j (512).
__global__ void gram_kernel(const float* __restrict__ ws_in, float* __restrict__ ws) {
    const float* Dn = ws_in + WS_DN;
    float* G = ws + WS_G;
    int i = blockIdx.x, j = threadIdx.x;
    float s = 0.f;
    #pragma unroll
    for (int d = 0; d < DIM; ++d)
        s = fmaf(Dn[d*KAT + i], Dn[d*KAT + j], s);
    G[i*KAT + j] = s;
}

// ---------------------------------------------------------------------------
// Kernel 3: merged zf permutation-gather (blocks 0..1023) + gamma zero-fill
// (blocks 1024..9215). One launch instead of two.
__global__ __launch_bounds__(256) void zg_kernel(const float* __restrict__ z_e,
                                                 float* __restrict__ out) {
    __shared__ float tile[64 * 33];   // [c][w], pad to 33 -> conflict-free
    int t = threadIdx.x;
    if (blockIdx.x < 1024) {
        int s = blockIdx.x;           // one (b,h) slab each
        int b = s >> 5, h = s & 31;
        int srcbase = b * 65536 + h * 32;
        #pragma unroll
        for (int i = 0; i < 8; ++i) {
            int e = t + i * 256;      // e = c*32 + w
            int c = e >> 5, w = e & 31;
            tile[c * 33 + w] = z_e[srcbase + c * 1024 + w];
        }
        __syncthreads();
        int obase = O_ZF + s * 2048;
        #pragma unroll
        for (int i = 0; i < 8; ++i) {
            int e = t + i * 256;      // e = w*64 + c
            out[obase + e] = tile[(e & 63) * 33 + (e >> 6)];
        }
    } else {
        float2* g2 = (float2*)(out + O_GAMMA);   // region only 8B-aligned
        int id = (blockIdx.x - 1024) * 256 + t;  // 8192 blocks' worth
        #pragma unroll
        for (int i = 0; i < 4; ++i)
            g2[id + i * 2097152] = make_float2(0.f, 0.f);
    }
}

// ---------------------------------------------------------------------------
// Kernel 4: fused h_bar + Batch-OMP. 8 columns per 256-thread block (LDS
// 18.4 KB -> 8 blocks/CU -> 32 waves/CU, 2x the old TLP); one wave per
// column, 2 columns/wave. Argmax: DPP max reduce, then a single-tie fast
// path (ballot + s_ff1 + readlane gives index AND signed winner) with the
// exact old DPP-min + sign-ballot as the tie slow path. Cholesky row via
// replicated w-recurrence from uniform (scalar) G loads.
__global__ __launch_bounds__(256) void omp_kernel(const float* __restrict__ z_e,
                                                  const float* __restrict__ ws,
                                                  float* __restrict__ out,
                                                  float* __restrict__ wsw) {
    const float* Dn  = ws + WS_DN;
    const float* DnT = ws + WS_DNT;
    const float* G   = ws + WS_G;
    float* acc = wsw + WS_ACC;

    __shared__ __align__(16) float xcols[DIM * CPB];  // [d][c]   2 KB
    __shared__ float hbar[CPB * KAT];                 // [c][a]  16 KB

    const int t = threadIdx.x;
    const int n_base = blockIdx.x * CPB;

    // ---- Phase 1: gather data columns
    #pragma unroll
    for (int i = 0; i < 2; ++i) {
        int e = t + i * 256;              // 0..511, e = d*8 + c
        int d = e >> 3, c = e & 7;
        int L = d * NCOL + n_base + c;
        int src = (L >> 16) * 65536 + (L & 63) * 1024 + (((L >> 11) & 31) << 5) + ((L >> 6) & 31);
        xcols[e] = z_e[src];
    }
    __syncthreads();

    // ---- Phase 2: h_bar tile (each thread: atoms t and t+256, 8 columns)
    {
        float a0[8], a1[8];
        #pragma unroll
        for (int i = 0; i < 8; ++i) { a0[i] = 0.f; a1[i] = 0.f; }
        const float4* xc4 = (const float4*)xcols;
        for (int d = 0; d < DIM; ++d) {
            float v0 = Dn[d * KAT + t];
            float v1 = Dn[d * KAT + 256 + t];
            float4 xa = xc4[d * 2 + 0];
            float4 xb = xc4[d * 2 + 1];
            a0[0] = fmaf(v0, xa.x, a0[0]);
            a0[1] = fmaf(v0, xa.y, a0[1]);
            a0[2] = fmaf(v0, xa.z, a0[2]);
            a0[3] = fmaf(v0, xa.w, a0[3]);
            a0[4] = fmaf(v0, xb.x, a0[4]);
            a0[5] = fmaf(v0, xb.y, a0[5]);
            a0[6] = fmaf(v0, xb.z, a0[6]);
            a0[7] = fmaf(v0, xb.w, a0[7]);
            a1[0] = fmaf(v1, xa.x, a1[0]);
            a1[1] = fmaf(v1, xa.y, a1[1]);
            a1[2] = fmaf(v1, xa.z, a1[2]);
            a1[3] = fmaf(v1, xa.w, a1[3]);
            a1[4] = fmaf(v1, xb.x, a1[4]);
            a1[5] = fmaf(v1, xb.y, a1[5]);
            a1[6] = fmaf(v1, xb.z, a1[6]);
            a1[7] = fmaf(v1, xb.w, a1[7]);
        }
        #pragma unroll
        for (int c = 0; c < 8; ++c) {
            hbar[c * KAT + t]       = a0[c];
            hbar[c * KAT + 256 + t] = a1[c];
        }
    }
    __syncthreads();

    // ---- Phase 3: OMP, one wave per column, 2 columns sequentially
    const int wv = t >> 6, lane = t & 63;
    float wv_sq = 0.f, wv_S = 0.f;

    #pragma unroll 1
    for (int cc = 0; cc < 2; ++cc) {
        const int col = wv * 2 + cc;
        const int n = n_base + col;
        const float* hbcol = hbar + col * KAT;

        float h[8];
        #pragma unroll
        for (int r = 0; r < 8; ++r) h[r] = hbcol[(r << 6) + lane];

        unsigned msk = 0;
        float uv[56];                 // u_0..u_6, uv[j*8+r]
        float Lr[28];                 // off-diag rows 1..7: Lr[i*(i-1)/2+j], j<i
        float invd[8], yv[8], xr[8];
        int Iv[8];

        #pragma unroll
        for (int k = 0; k < 8; ++k) {
            // local argmax over this lane's 8 slots (track signed winner)
            float bv = -1.f; int bi = 0; float hb = 0.f;
            #pragma unroll
            for (int r = 0; r < 8; ++r) {
                float av = ((msk >> r) & 1) ? -1.f : fabsf(h[r]);
                bool gt = av > bv;
                bv = gt ? av : bv;
                bi = gt ? ((r << 6) | lane) : bi;
                hb = gt ? h[r] : hb;
            }
            // wave max; single-tie fast path avoids the 6-stage min reduce
            float maxv = wave_max_bcast_f32(bv);
            unsigned long long tie = __ballot(bv == maxv);
            int idx; float hwin;
            if (__popcll(tie) == 1) {
                int sl = __ffsll((unsigned long long)tie) - 1;     // uniform
                idx  = __builtin_amdgcn_readlane(bi, sl);
                hwin = __int_as_float(__builtin_amdgcn_readlane(__float_as_int(hb), sl));
            } else {
                // exact first-index tie-break (reference semantics)
                unsigned cand = (bv == maxv) ? (unsigned)bi : 0xffffffffu;
                idx = (int)wave_min_bcast_u32(cand);
                unsigned long long sm = __ballot((bv == maxv) && (bi == idx) && (hb < 0.f));
                hwin = (sm != 0ull) ? -maxv : maxv;
            }

            if ((idx & 63) == lane) msk |= 1u << (idx >> 6);
            Iv[k] = idx;

            const float* grow = G + idx * KAT;   // scalar base
            // prefetch new G row (coalesced; also warms L1/L2 for grow[Iv[i]])
            float gk[8];
            if (k < 7) {
                #pragma unroll
                for (int r = 0; r < 8; ++r) gk[r] = grow[(r << 6) + lane];
            }

            // replicated Cholesky rank-1 extension (uniform scalar loads)
            float Lk[7];
            if (k == 0) {
                invd[0] = 1.f;
            } else {
                float s2 = 0.f;
                #pragma unroll
                for (int i = 0; i < 7; ++i) if (i < k) {
                    float a = grow[Iv[i]];              // == G[Iv[i]][idx]
                    #pragma unroll
                    for (int j = 0; j < 7; ++j) if (j < i) a = fmaf(-Lr[i*(i-1)/2 + j], Lk[j], a);
                    Lk[i] = a * invd[i];
                    s2 = fmaf(Lk[i], Lk[i], s2);
                }
                #pragma unroll
                for (int j = 0; j < 7; ++j) if (j < k) Lr[k*(k-1)/2 + j] = Lk[j];
                invd[k] = 1.f / sqrtf(1.f - s2);
            }
            yv[k] = hwin * invd[k];

            // u_k and incremental h update (not needed after last pick)
            if (k < 7) {
                #pragma unroll
                for (int r = 0; r < 8; ++r) {
                    float a = gk[r];
                    #pragma unroll
                    for (int j = 0; j < 7; ++j) if (j < k) a = fmaf(-Lk[j], uv[j*8 + r], a);
                    a *= invd[k];
                    uv[k*8 + r] = a;
                    h[r] = fmaf(-yv[k], a, h[r]);
                }
            }
        }

        // single back solve: L^T xr = yv
        #pragma unroll
        for (int i = 7; i >= 0; --i) {
            float a = yv[i];
            #pragma unroll
            for (int j = 0; j < 8; ++j) if (j > i) a = fmaf(-Lr[j*(j-1)/2 + i], xr[j], a);
            xr[i] = a * invd[i];
        }

        // ---- outputs for this column ----
        #pragma unroll
        for (int j = 0; j < 8; ++j)
            if (lane == j) out[O_GAMMA + Iv[j] * NCOL + n] = xr[j];

        // recon (lane = d), through the output permutation
        float rec = 0.f;
        #pragma unroll
        for (int j = 0; j < 8; ++j)
            rec = fmaf(xr[j], DnT[Iv[j] * DIM + lane], rec);
        int L = lane * NCOL + n;
        int perm = (L >> 16) * 65536 + (L & 63) * 1024 + (((L >> 11) & 31) << 5) + ((L >> 6) & 31);
        out[O_RECON + perm] = rec;

        // squared-error partial (all-VALU DPP sum; result uniform)
        float xd = xcols[lane * CPB + col];
        float diff = rec - xd;
        wv_sq += wave_sum_bcast_f32(diff * diff);

        // softmax-entropy: 8 nnz + 504 zeros, parallel over lanes 0..7
        {
            float m = 0.f;
            #pragma unroll
            for (int j = 0; j < 8; ++j) m = fmaxf(m, xr[j]);
            float xsel = 0.f;
            #pragma unroll
            for (int j = 0; j < 8; ++j) xsel = (lane == j) ? xr[j] : xsel;
            float e = (lane < 8) ? expf(xsel - m) : 0.f;
            float se = sum8_all_f32(e);          // valid on lanes 0..7
            float e0 = expf(-m);
            float Z = fmaf(504.f, e0, se);
            float invZ = 1.f / Z;
            float p = e * invZ;
            float tq = (lane < 8) ? p * logf(p + 1e-10f) : 0.f;
            tq = sum8_all_f32(tq);
            if (lane == 0) {
                float p0 = e0 * invZ;
                wv_S += tq + 504.f * p0 * logf(p0 + 1e-10f);
            }
        }
    }

    if (lane == 0) {
        atomicAdd(&acc[0], wv_sq);
        atomicAdd(&acc[1], wv_S);
    }
}

// ---------------------------------------------------------------------------
// Kernel 5: finalize scalars.
__global__ void fin_kernel(const float* __restrict__ ws, const float* __restrict__ beta,
                           float* __restrict__ out) {
    const float* acc = ws + WS_ACC;
    float mse = acc[0] / 2097152.f;                 // mean over 64*32768
    out[O_LOSS] = mse * 0.25f + beta[0] * mse;      // e_latent*cost + beta*q
    out[O_PERP] = expf(-acc[1] / 32768.f);
}

// ---------------------------------------------------------------------------
extern "C" void kernel_launch(void* const* d_in, const int* in_sizes, int n_in,
                              void* d_out, int out_size, void* d_ws, size_t ws_size,
                              hipStream_t stream) {
    const float* z_e  = (const float*)d_in[0];
    const float* dict = (const float*)d_in[1];
    const float* beta = (const float*)d_in[2];
    float* out = (float*)d_out;
    float* ws  = (float*)d_ws;

    prep_kernel<<<8, 64, 0, stream>>>(dict, ws);
    gram_kernel<<<512, 512, 0, stream>>>(ws, ws);
    zg_kernel<<<9216, 256, 0, stream>>>(z_e, out);
    omp_kernel<<<4096, 256, 0, stream>>>(z_e, ws, out, ws);
    fin_kernel<<<1, 1, 0, stream>>>(ws, beta, out);
}

// Round 3
// 357.683 us; speedup vs baseline: 1.5374x; 1.5374x over previous
//
#include <hip/hip_runtime.h>
#include <math.h>

// Problem constants
#define NCOL 32768          // N = 32*32*32 columns
#define KAT  512            // dictionary atoms
#define DIM  64             // embedding dim
#define CPB  16             // columns per omp block (LDS 36 KB -> 4 blocks/CU)

// Output flat offsets (fp32 elements)
#define O_LOSS  0
#define O_RECON 1
#define O_ZF    2097153     // 1 + 2097152
#define O_PERP  4194305
#define O_GAMMA 4194306

// Workspace layout (fp32 elements)
#define WS_DN   0           // Dn  [64][512]
#define WS_DNT  32768       // DnT [512][64]
#define WS_G    65536       // G   [512][512]
#define WS_ACC  327680      // acc[0]=sum((recon-zf)^2), acc[1]=sum_n S_n

// ---------------------------------------------------------------------------
// DPP wave-64 reductions (all-VALU; result broadcast via readlane)
__device__ __forceinline__ float wave_max_bcast_f32(float v) {
    int x = __float_as_int(v);
    int t;
    t = __builtin_amdgcn_update_dpp(x, x, 0x111, 0xf, 0xf, false);  // row_shr:1
    x = __float_as_int(fmaxf(__int_as_float(x), __int_as_float(t)));
    t = __builtin_amdgcn_update_dpp(x, x, 0x112, 0xf, 0xf, false);  // row_shr:2
    x = __float_as_int(fmaxf(__int_as_float(x), __int_as_float(t)));
    t = __builtin_amdgcn_update_dpp(x, x, 0x114, 0xf, 0xf, false);  // row_shr:4
    x = __float_as_int(fmaxf(__int_as_float(x), __int_as_float(t)));
    t = __builtin_amdgcn_update_dpp(x, x, 0x118, 0xf, 0xf, false);  // row_shr:8
    x = __float_as_int(fmaxf(__int_as_float(x), __int_as_float(t)));
    t = __builtin_amdgcn_update_dpp(x, x, 0x142, 0xa, 0xf, false);  // row_bcast:15
    x = __float_as_int(fmaxf(__int_as_float(x), __int_as_float(t)));
    t = __builtin_amdgcn_update_dpp(x, x, 0x143, 0xc, 0xf, false);  // row_bcast:31
    x = __float_as_int(fmaxf(__int_as_float(x), __int_as_float(t)));
    return __int_as_float(__builtin_amdgcn_readlane(x, 63));
}

__device__ __forceinline__ unsigned wave_min_bcast_u32(unsigned v) {
    int x = (int)v;
    int t;
    t = __builtin_amdgcn_update_dpp(x, x, 0x111, 0xf, 0xf, false);
    x = (int)min((unsigned)x, (unsigned)t);
    t = __builtin_amdgcn_update_dpp(x, x, 0x112, 0xf, 0xf, false);
    x = (int)min((unsigned)x, (unsigned)t);
    t = __builtin_amdgcn_update_dpp(x, x, 0x114, 0xf, 0xf, false);
    x = (int)min((unsigned)x, (unsigned)t);
    t = __builtin_amdgcn_update_dpp(x, x, 0x118, 0xf, 0xf, false);
    x = (int)min((unsigned)x, (unsigned)t);
    t = __builtin_amdgcn_update_dpp(x, x, 0x142, 0xa, 0xf, false);
    x = (int)min((unsigned)x, (unsigned)t);
    t = __builtin_amdgcn_update_dpp(x, x, 0x143, 0xc, 0xf, false);
    x = (int)min((unsigned)x, (unsigned)t);
    return (unsigned)__builtin_amdgcn_readlane(x, 63);
}

// Full-wave sum, result broadcast via readlane.
__device__ __forceinline__ float wave_sum_bcast_f32(float v) {
    int x = __float_as_int(v);
    int t;
    t = __builtin_amdgcn_update_dpp(x, x, 0x0B1, 0xf, 0xf, false);  // quad_perm [1,0,3,2]
    x = __float_as_int(__int_as_float(x) + __int_as_float(t));
    t = __builtin_amdgcn_update_dpp(x, x, 0x04E, 0xf, 0xf, false);  // quad_perm [2,3,0,1]
    x = __float_as_int(__int_as_float(x) + __int_as_float(t));
    t = __builtin_amdgcn_update_dpp(x, x, 0x141, 0xf, 0xf, false);  // row_half_mirror
    x = __float_as_int(__int_as_float(x) + __int_as_float(t));
    t = __builtin_amdgcn_update_dpp(x, x, 0x140, 0xf, 0xf, false);  // row_mirror
    x = __float_as_int(__int_as_float(x) + __int_as_float(t));
    t = __builtin_amdgcn_update_dpp(x, x, 0x142, 0xa, 0xf, false);  // row_bcast:15
    x = __float_as_int(__int_as_float(x) + __int_as_float(t));
    t = __builtin_amdgcn_update_dpp(x, x, 0x143, 0xc, 0xf, false);  // row_bcast:31
    x = __float_as_int(__int_as_float(x) + __int_as_float(t));
    return __int_as_float(__builtin_amdgcn_readlane(x, 63));
}

// Sum over each 8-lane group, result on ALL lanes of the group (3 DPP stages).
__device__ __forceinline__ float sum8_all_f32(float v) {
    int x = __float_as_int(v);
    int t;
    t = __builtin_amdgcn_update_dpp(x, x, 0x0B1, 0xf, 0xf, false);  // xor1
    x = __float_as_int(__int_as_float(x) + __int_as_float(t));
    t = __builtin_amdgcn_update_dpp(x, x, 0x04E, 0xf, 0xf, false);  // xor2
    x = __float_as_int(__int_as_float(x) + __int_as_float(t));
    t = __builtin_amdgcn_update_dpp(x, x, 0x141, 0xf, 0xf, false);  // xor4 (half_mirror)
    x = __float_as_int(__int_as_float(x) + __int_as_float(t));
    return __int_as_float(x);
}

// ---------------------------------------------------------------------------
// Kernel 1: normalize dictionary columns -> Dn, DnT; zero accumulators.
// 8 blocks x 64 threads (spread across CUs instead of 1 serial block).
__global__ void prep_kernel(const float* __restrict__ dict, float* __restrict__ ws) {
    float* Dn  = ws + WS_DN;
    float* DnT = ws + WS_DNT;
    float* acc = ws + WS_ACC;
    int a = blockIdx.x * 64 + threadIdx.x;
    if (blockIdx.x == 0 && threadIdx.x < 2) acc[threadIdx.x] = 0.f;
    float s = 0.f;
    #pragma unroll
    for (int d = 0; d < DIM; ++d) { float v = dict[d*KAT + a]; s += v * v; }
    float nrm = sqrtf(s);
    #pragma unroll
    for (int d = 0; d < DIM; ++d) {
        float v = dict[d*KAT + a] / nrm;
        Dn[d*KAT + a]  = v;
        DnT[a*DIM + d] = v;
    }
}

// ---------------------------------------------------------------------------
// Kernel 2: G = Dn^T Dn.  block = row i (512 blocks), thread = col j (512).
__global__ void gram_kernel(const float* __restrict__ ws_in, float* __restrict__ ws) {
    const float* Dn = ws_in + WS_DN;
    float* G = ws + WS_G;
    int i = blockIdx.x, j = threadIdx.x;
    float s = 0.f;
    #pragma unroll
    for (int d = 0; d < DIM; ++d)
        s = fmaf(Dn[d*KAT + i], Dn[d*KAT + j], s);
    G[i*KAT + j] = s;
}

// ---------------------------------------------------------------------------
// Kernel 3: merged zf permutation-gather (blocks 0..1023) + gamma zero-fill
// (blocks 1024..9215). One launch instead of two.
__global__ __launch_bounds__(256) void zg_kernel(const float* __restrict__ z_e,
                                                 float* __restrict__ out) {
    __shared__ float tile[64 * 33];   // [c][w], pad to 33 -> conflict-free
    int t = threadIdx.x;
    if (blockIdx.x < 1024) {
        int s = blockIdx.x;           // one (b,h) slab each
        int b = s >> 5, h = s & 31;
        int srcbase = b * 65536 + h * 32;
        #pragma unroll
        for (int i = 0; i < 8; ++i) {
            int e = t + i * 256;      // e = c*32 + w
            int c = e >> 5, w = e & 31;
            tile[c * 33 + w] = z_e[srcbase + c * 1024 + w];
        }
        __syncthreads();
        int obase = O_ZF + s * 2048;
        #pragma unroll
        for (int i = 0; i < 8; ++i) {
            int e = t + i * 256;      // e = w*64 + c
            out[obase + e] = tile[(e & 63) * 33 + (e >> 6)];
        }
    } else {
        float2* g2 = (float2*)(out + O_GAMMA);   // region only 8B-aligned
        int id = (blockIdx.x - 1024) * 256 + t;  // 8192 blocks' worth
        #pragma unroll
        for (int i = 0; i < 4; ++i)
            g2[id + i * 2097152] = make_float2(0.f, 0.f);
    }
}

// ---------------------------------------------------------------------------
// Kernel 4: fused h_bar + Batch-OMP. 16 columns per 256-thread block; one wave
// per column, 4 columns/wave. __launch_bounds__(256,4): LDS already caps at
// 4 blocks/CU (16 waves = 4 waves/SIMD), so VGPRs up to 128 are FREE — this
// lifts the compiler's default 64-VGPR budget that was spilling uv[56]+Lr[28]
// to scratch (round-0/1 counters: VGPR=64, WRITE_SIZE 32 MB vs ~9 MB of real
// output => ~23 MB/dispatch scratch traffic on the serial OMP critical path).
__global__ __launch_bounds__(256, 4) void omp_kernel(const float* __restrict__ z_e,
                                                     const float* __restrict__ ws,
                                                     float* __restrict__ out,
                                                     float* __restrict__ wsw) {
    const float* Dn  = ws + WS_DN;
    const float* DnT = ws + WS_DNT;
    const float* G   = ws + WS_G;
    float* acc = wsw + WS_ACC;

    __shared__ __align__(16) float xcols[DIM * CPB];  // [d][c]   4 KB
    __shared__ float hbar[CPB * KAT];                 // [c][a]  32 KB

    const int t = threadIdx.x;
    const int n_base = blockIdx.x * CPB;

    // ---- Phase 1: gather data columns
    #pragma unroll
    for (int i = 0; i < 4; ++i) {
        int e = t + i * 256;              // 0..1023, e = d*16 + c
        int d = e >> 4, c = e & 15;
        int L = d * NCOL + n_base + c;
        int src = (L >> 16) * 65536 + (L & 63) * 1024 + (((L >> 11) & 31) << 5) + ((L >> 6) & 31);
        xcols[e] = z_e[src];
    }
    __syncthreads();

    // ---- Phase 2: h_bar tile (Dn read once per block)
    {
        float a0[16], a1[16];
        #pragma unroll
        for (int i = 0; i < 16; ++i) { a0[i] = 0.f; a1[i] = 0.f; }
        const float4* xc4 = (const float4*)xcols;
        for (int d = 0; d < DIM; ++d) {
            float v0 = Dn[d * KAT + t];
            float v1 = Dn[d * KAT + 256 + t];
            #pragma unroll
            for (int q = 0; q < 4; ++q) {
                float4 xv = xc4[d * 4 + q];
                a0[q*4+0] = fmaf(v0, xv.x, a0[q*4+0]);
                a0[q*4+1] = fmaf(v0, xv.y, a0[q*4+1]);
                a0[q*4+2] = fmaf(v0, xv.z, a0[q*4+2]);
                a0[q*4+3] = fmaf(v0, xv.w, a0[q*4+3]);
                a1[q*4+0] = fmaf(v1, xv.x, a1[q*4+0]);
                a1[q*4+1] = fmaf(v1, xv.y, a1[q*4+1]);
                a1[q*4+2] = fmaf(v1, xv.z, a1[q*4+2]);
                a1[q*4+3] = fmaf(v1, xv.w, a1[q*4+3]);
            }
        }
        #pragma unroll
        for (int c = 0; c < 16; ++c) {
            hbar[c * KAT + t]       = a0[c];
            hbar[c * KAT + 256 + t] = a1[c];
        }
    }
    __syncthreads();

    // ---- Phase 3: OMP, one wave per column, 4 columns sequentially
    const int wv = t >> 6, lane = t & 63;
    float wv_sq = 0.f, wv_S = 0.f;

    #pragma unroll 1
    for (int cc = 0; cc < 4; ++cc) {
        const int col = wv * 4 + cc;
        const int n = n_base + col;
        const float* hbcol = hbar + col * KAT;

        float h[8];
        #pragma unroll
        for (int r = 0; r < 8; ++r) h[r] = hbcol[(r << 6) + lane];

        unsigned msk = 0;
        float uv[56];                 // u_0..u_6, uv[j*8+r]
        float Lr[28];                 // off-diag rows 1..7: Lr[i*(i-1)/2+j], j<i
        float invd[8], yv[8], xr[8];
        int Iv[8];

        #pragma unroll
        for (int k = 0; k < 8; ++k) {
            // local argmax over this lane's 8 slots (track signed winner)
            float bv = -1.f; int bi = 0; float hb = 0.f;
            #pragma unroll
            for (int r = 0; r < 8; ++r) {
                float av = ((msk >> r) & 1) ? -1.f : fabsf(h[r]);
                bool gt = av > bv;
                bv = gt ? av : bv;
                bi = gt ? ((r << 6) | lane) : bi;
                hb = gt ? h[r] : hb;
            }
            // wave max; single-tie fast path avoids the 6-stage min reduce
            float maxv = wave_max_bcast_f32(bv);
            unsigned long long tie = __ballot(bv == maxv);
            int idx; float hwin;
            if (__popcll(tie) == 1) {
                int sl = __ffsll((unsigned long long)tie) - 1;     // uniform
                idx  = __builtin_amdgcn_readlane(bi, sl);
                hwin = __int_as_float(__builtin_amdgcn_readlane(__float_as_int(hb), sl));
            } else {
                // exact first-index tie-break (reference semantics)
                unsigned cand = (bv == maxv) ? (unsigned)bi : 0xffffffffu;
                idx = (int)wave_min_bcast_u32(cand);
                unsigned long long sm = __ballot((bv == maxv) && (bi == idx) && (hb < 0.f));
                hwin = (sm != 0ull) ? -maxv : maxv;
            }

            if ((idx & 63) == lane) msk |= 1u << (idx >> 6);
            Iv[k] = idx;

            const float* grow = G + idx * KAT;   // scalar base
            // prefetch new G row (coalesced; also warms L1/L2 for grow[Iv[i]])
            float gk[8];
            if (k < 7) {
                #pragma unroll
                for (int r = 0; r < 8; ++r) gk[r] = grow[(r << 6) + lane];
            }

            // replicated Cholesky rank-1 extension (uniform scalar loads)
            float Lk[7];
            if (k == 0) {
                invd[0] = 1.f;
            } else {
                float s2 = 0.f;
                #pragma unroll
                for (int i = 0; i < 7; ++i) if (i < k) {
                    float a = grow[Iv[i]];              // == G[Iv[i]][idx]
                    #pragma unroll
                    for (int j = 0; j < 7; ++j) if (j < i) a = fmaf(-Lr[i*(i-1)/2 + j], Lk[j], a);
                    Lk[i] = a * invd[i];
                    s2 = fmaf(Lk[i], Lk[i], s2);
                }
                #pragma unroll
                for (int j = 0; j < 7; ++j) if (j < k) Lr[k*(k-1)/2 + j] = Lk[j];
                invd[k] = 1.f / sqrtf(1.f - s2);
            }
            yv[k] = hwin * invd[k];

            // u_k and incremental h update (not needed after last pick)
            if (k < 7) {
                #pragma unroll
                for (int r = 0; r < 8; ++r) {
                    float a = gk[r];
                    #pragma unroll
                    for (int j = 0; j < 7; ++j) if (j < k) a = fmaf(-Lk[j], uv[j*8 + r], a);
                    a *= invd[k];
                    uv[k*8 + r] = a;
                    h[r] = fmaf(-yv[k], a, h[r]);
                }
            }
        }

        // single back solve: L^T xr = yv
        #pragma unroll
        for (int i = 7; i >= 0; --i) {
            float a = yv[i];
            #pragma unroll
            for (int j = 0; j < 8; ++j) if (j > i) a = fmaf(-Lr[j*(j-1)/2 + i], xr[j], a);
            xr[i] = a * invd[i];
        }

        // ---- outputs for this column ----
        #pragma unroll
        for (int j = 0; j < 8; ++j)
            if (lane == j) out[O_GAMMA + Iv[j] * NCOL + n] = xr[j];

        // recon (lane = d), through the output permutation
        float rec = 0.f;
        #pragma unroll
        for (int j = 0; j < 8; ++j)
            rec = fmaf(xr[j], DnT[Iv[j] * DIM + lane], rec);
        int L = lane * NCOL + n;
        int perm = (L >> 16) * 65536 + (L & 63) * 1024 + (((L >> 11) & 31) << 5) + ((L >> 6) & 31);
        out[O_RECON + perm] = rec;

        // squared-error partial (all-VALU DPP sum; result uniform)
        float xd = xcols[lane * CPB + col];
        float diff = rec - xd;
        wv_sq += wave_sum_bcast_f32(diff * diff);

        // softmax-entropy: 8 nnz + 504 zeros, parallel over lanes 0..7
        {
            float m = 0.f;
            #pragma unroll
            for (int j = 0; j < 8; ++j) m = fmaxf(m, xr[j]);
            float xsel = 0.f;
            #pragma unroll
            for (int j = 0; j < 8; ++j) xsel = (lane == j) ? xr[j] : xsel;
            float e = (lane < 8) ? expf(xsel - m) : 0.f;
            float se = sum8_all_f32(e);          // valid on lanes 0..7
            float e0 = expf(-m);
            float Z = fmaf(504.f, e0, se);
            float invZ = 1.f / Z;
            float p = e * invZ;
            float tq = (lane < 8) ? p * logf(p + 1e-10f) : 0.f;
            tq = sum8_all_f32(tq);
            if (lane == 0) {
                float p0 = e0 * invZ;
                wv_S += tq + 504.f * p0 * logf(p0 + 1e-10f);
            }
        }
    }

    if (lane == 0) {
        atomicAdd(&acc[0], wv_sq);
        atomicAdd(&acc[1], wv_S);
    }
}

// ---------------------------------------------------------------------------
// Kernel 5: finalize scalars.
__global__ void fin_kernel(const float* __restrict__ ws, const float* __restrict__ beta,
                           float* __restrict__ out) {
    const float* acc = ws + WS_ACC;
    float mse = acc[0] / 2097152.f;                 // mean over 64*32768
    out[O_LOSS] = mse * 0.25f + beta[0] * mse;      // e_latent*cost + beta*q
    out[O_PERP] = expf(-acc[1] / 32768.f);
}

// ---------------------------------------------------------------------------
extern "C" void kernel_launch(void* const* d_in, const int* in_sizes, int n_in,
                              void* d_out, int out_size, void* d_ws, size_t ws_size,
                              hipStream_t stream) {
    const float* z_e  = (const float*)d_in[0];
    const float* dict = (const float*)d_in[1];
    const float* beta = (const float*)d_in[2];
    float* out = (float*)d_out;
    float* ws  = (float*)d_ws;

    prep_kernel<<<8, 64, 0, stream>>>(dict, ws);
    gram_kernel<<<512, 512, 0, stream>>>(ws, ws);
    zg_kernel<<<9216, 256, 0, stream>>>(z_e, out);
    omp_kernel<<<2048, 256, 0, stream>>>(z_e, ws, out, ws);
    fin_kernel<<<1, 1, 0, stream>>>(ws, beta, out);
}